// Round 6
// baseline (120.572 us; speedup 1.0000x reference)
//
#include <hip/hip_runtime.h>
#include <math.h>

#define DD 4096
#define EE 64
#define NTOK 8192
#define BM 256           // tokens per block (lane owns 4: 64 lanes x 4)
#define KC 16            // K-chunk staged in LDS
#define XP 260           // xs row stride (words): pad kills write conflicts
#define WP 68            // wsh row stride
#define NMB (NTOK / BM)  // 32 m-blocks
#define TAU 1e-3f        // near-tie flag threshold (f32 err worst-case ~1e-5)

// ---------------------------------------------------------------------------
// gemm (f32): block = 256 tok x 64 exp. 4 waves; lane = 4 tokens, wave = 16
// experts. Per k: 1 conflict-free b128 x-read + 4 wave-uniform (broadcast)
// W-reads + 64 FMAs -> VALU-bound (~0.3 B/FMA of LDS traffic).
// Partials (f32, deterministic) -> part[ks][token][e].
// ---------------------------------------------------------------------------
__global__ __launch_bounds__(256, 2) void moirai_gemm(
        const float* __restrict__ x, const float* __restrict__ W,
        float* __restrict__ part, int* __restrict__ count, int kslen) {
    __shared__ float xs[KC][XP];    // 16.25 KB
    __shared__ float wsh[KC][WP];   //  4.25 KB

    const int t    = threadIdx.x;
    const int lane = t & 63;
    const int wv   = t >> 6;             // wave 0..3 -> experts 16*wv..+15
    const int mblk = blockIdx.x & (NMB - 1);
    const int ks   = blockIdx.x >> 5;    // grid = NMB * KS, NMB = 32
    const int m0   = mblk * BM;
    const int k0   = ks * kslen;

    if (blockIdx.x == 0 && t == 0) *count = 0;

    const int srow = t >> 2;             // staging row base 0..63
    const int ssg  = t & 3;              // 16B segment within 16-f32 k-slice

    float acc[4][16];
#pragma unroll
    for (int mm = 0; mm < 4; mm++)
#pragma unroll
        for (int ee = 0; ee < 16; ee++) acc[mm][ee] = 0.0f;

    const int nch = kslen / KC;
    float4 xr[4], wr;

    auto load_regs = [&](int c) {
        const int kb = k0 + c * KC + ssg * 4;
#pragma unroll
        for (int i = 0; i < 4; i++)      // x rows srow, srow+64, +128, +192
            xr[i] = *(const float4*)(x + (size_t)(m0 + srow + i * 64) * DD + kb);
        wr = *(const float4*)(W + (size_t)srow * DD + kb);
    };
    auto store_lds = [&]() {
#pragma unroll
        for (int i = 0; i < 4; i++) {
            const int rr = srow + i * 64;
            xs[ssg * 4 + 0][rr] = xr[i].x; xs[ssg * 4 + 1][rr] = xr[i].y;
            xs[ssg * 4 + 2][rr] = xr[i].z; xs[ssg * 4 + 3][rr] = xr[i].w;
        }
        wsh[ssg * 4 + 0][srow] = wr.x; wsh[ssg * 4 + 1][srow] = wr.y;
        wsh[ssg * 4 + 2][srow] = wr.z; wsh[ssg * 4 + 3][srow] = wr.w;
    };

    load_regs(0);
    store_lds();
    __syncthreads();

    for (int c = 0; c < nch; c++) {
        if (c + 1 < nch) load_regs(c + 1);   // global prefetch under compute

#pragma unroll 4
        for (int k = 0; k < KC; k++) {
            const float4 xa = *(const float4*)&xs[k][lane * 4];
            const float4 w0 = *(const float4*)&wsh[k][wv * 16 + 0];
            const float4 w1 = *(const float4*)&wsh[k][wv * 16 + 4];
            const float4 w2 = *(const float4*)&wsh[k][wv * 16 + 8];
            const float4 w3 = *(const float4*)&wsh[k][wv * 16 + 12];
            const float xv[4] = {xa.x, xa.y, xa.z, xa.w};
            const float wvv[16] = {w0.x, w0.y, w0.z, w0.w, w1.x, w1.y, w1.z, w1.w,
                                   w2.x, w2.y, w2.z, w2.w, w3.x, w3.y, w3.z, w3.w};
#pragma unroll
            for (int mm = 0; mm < 4; mm++)
#pragma unroll
                for (int ee = 0; ee < 16; ee++)
                    acc[mm][ee] = fmaf(xv[mm], wvv[ee], acc[mm][ee]);
        }

        if (c + 1 < nch) {
            __syncthreads();     // all reads of current chunk done
            store_lds();
            __syncthreads();     // staging visible
        }
    }

    // epilogue: lane writes 4 token-rows x 16 experts (4x b128 each row)
#pragma unroll
    for (int mm = 0; mm < 4; mm++) {
        float* po = part + ((size_t)ks * NTOK + (m0 + lane * 4 + mm)) * EE + wv * 16;
#pragma unroll
        for (int j = 0; j < 4; j++) {
            float4 o = {acc[mm][j * 4 + 0], acc[mm][j * 4 + 1],
                        acc[mm][j * 4 + 2], acc[mm][j * 4 + 3]};
            *(float4*)(po + j * 4) = o;
        }
    }
}

// ---------------------------------------------------------------------------
// topk pass 1: wave per token, lane = expert. f32 sum of KS partials + bias
// -> top-2 + third-max. Near-tie rows appended to flagged list (fix kernel
// overwrites them). Output: [gate_probs 16384 f32][indices-as-f32 16384].
// ---------------------------------------------------------------------------
__global__ void moirai_topk(const float* __restrict__ part,
                            const float* __restrict__ bias,
                            float* __restrict__ out,
                            int* __restrict__ count, int* __restrict__ list,
                            int KS) {
    const int lane  = threadIdx.x & 63;
    const int token = blockIdx.x * 4 + (threadIdx.x >> 6);

    float v = bias[lane];
    for (int ks = 0; ks < KS; ks++)
        v += part[((size_t)ks * NTOK + token) * EE + lane];

    // f32 top-2 butterfly with jax tie-break (lower index wins ties)
    float v1 = v, v2 = -3.4e38f;
    int   i1 = lane, i2 = 127;
#pragma unroll
    for (int off = 1; off < 64; off <<= 1) {
        float u1 = __shfl_xor(v1, off);
        float u2 = __shfl_xor(v2, off);
        int   j1 = __shfl_xor(i1, off);
        int   j2 = __shfl_xor(i2, off);
        bool u1_beats_v1 = (u1 > v1) || (u1 == v1 && j1 < i1);
        if (u1_beats_v1) {
            bool v1_beats_u2 = (v1 > u2) || (v1 == u2 && i1 < j2);
            if (v1_beats_u2) { v2 = v1; i2 = i1; }
            else             { v2 = u2; i2 = j2; }
            v1 = u1; i1 = j1;
        } else {
            bool u1_beats_v2 = (u1 > v2) || (u1 == v2 && j1 < i2);
            if (u1_beats_v2) { v2 = u1; i2 = j1; }
        }
    }

    // third-largest value (exclude top-2 by index)
    float ve = (lane == i1 || lane == i2) ? -3.4e38f : v;
#pragma unroll
    for (int off = 1; off < 64; off <<= 1)
        ve = fmaxf(ve, __shfl_xor(ve, off));

    if (lane == 0) {
        if ((v1 - v2 < TAU) || (v2 - ve < TAU)) {
            int pos = atomicAdd(count, 1);
            list[pos] = token;
        }
        double ex = exp((double)v2 - (double)v1);   // v1 >= v2 -> stable
        double s  = 1.0 + ex;
        out[token * 2 + 0] = (float)(1.0 / s);
        out[token * 2 + 1] = (float)(ex / s);
        out[NTOK * 2 + token * 2 + 0] = (float)i1;
        out[NTOK * 2 + token * 2 + 1] = (float)i2;
    }
}

// ---------------------------------------------------------------------------
// fix: exact f64 recompute of flagged rows, one block (1024 thr) per row.
// thread t: expert t&63, k-slice t>>6 (16 x 256). LDS reduce -> wave 0 does
// f64 top-2 (validated tie-break) and overwrites the row's outputs.
// ---------------------------------------------------------------------------
__global__ __launch_bounds__(1024) void moirai_fix(
        const float* __restrict__ x, const float* __restrict__ W,
        const float* __restrict__ bias,
        const int* __restrict__ count, const int* __restrict__ list,
        float* __restrict__ out) {
    __shared__ double red[16][EE];

    const int t = threadIdx.x;
    const int e = t & 63;
    const int q = t >> 6;           // 16 k-slices of 256
    const int n = *count;

    for (int idx = blockIdx.x; idx < n; idx += gridDim.x) {
        const int token = list[idx];
        const float* xr = x + (size_t)token * DD + q * (DD / 16);
        const float* wr = W + (size_t)e * DD + q * (DD / 16);

        double a0 = 0.0, a1 = 0.0, a2 = 0.0, a3 = 0.0;
#pragma unroll 4
        for (int k = 0; k < DD / 16; k += 4) {
            const float4 xv = *(const float4*)(xr + k);
            const float4 wv = *(const float4*)(wr + k);
            a0 += (double)xv.x * (double)wv.x;
            a1 += (double)xv.y * (double)wv.y;
            a2 += (double)xv.z * (double)wv.z;
            a3 += (double)xv.w * (double)wv.w;
        }
        red[q][e] = (a0 + a1) + (a2 + a3);
        __syncthreads();

        if (q == 0) {
            double vd = 0.0;
#pragma unroll
            for (int qq = 0; qq < 16; qq++) vd += red[qq][e];   // fixed order
            vd += (double)bias[e];

            double e1 = vd, e2 = -1.0e300;
            int    f1 = e,  f2 = 127;
#pragma unroll
            for (int off = 1; off < 64; off <<= 1) {
                double u1 = __shfl_xor(e1, off);
                double u2 = __shfl_xor(e2, off);
                int    j1 = __shfl_xor(f1, off);
                int    j2 = __shfl_xor(f2, off);
                bool u1_beats_e1 = (u1 > e1) || (u1 == e1 && j1 < f1);
                if (u1_beats_e1) {
                    bool e1_beats_u2 = (e1 > u2) || (e1 == u2 && f1 < j2);
                    if (e1_beats_u2) { e2 = e1; f2 = f1; }
                    else             { e2 = u2; f2 = j2; }
                    e1 = u1; f1 = j1;
                } else {
                    bool u1_beats_e2 = (u1 > e2) || (u1 == e2 && j1 < f2);
                    if (u1_beats_e2) { e2 = u1; f2 = j1; }
                }
            }

            if (e == 0) {
                double ex = exp(e2 - e1);
                double s  = 1.0 + ex;
                out[token * 2 + 0] = (float)(1.0 / s);
                out[token * 2 + 1] = (float)(ex / s);
                out[NTOK * 2 + token * 2 + 0] = (float)f1;
                out[NTOK * 2 + token * 2 + 1] = (float)f2;
            }
        }
        __syncthreads();   // LDS reuse guard for next grid-stride iteration
    }
}

// ---------------------------------------------------------------------------
extern "C" void kernel_launch(void* const* d_in, const int* in_sizes, int n_in,
                              void* d_out, int out_size, void* d_ws, size_t ws_size,
                              hipStream_t stream) {
    const float* x = (const float*)d_in[0];
    const float* W = (const float*)d_in[1];
    const float* b = (const float*)d_in[2];
    float* out = (float*)d_out;

    // ws layout: [count 4B | list NTOK*4B] padded to 64 KB, then partials
    const size_t HDR = 65536;
    int*   count = (int*)d_ws;
    int*   list  = (int*)d_ws + 1;
    float* part  = (float*)((char*)d_ws + HDR);

    int KS = 16;  // K-split; kslen stays a multiple of KC
    while (KS > 1 && HDR + (size_t)KS * NTOK * EE * 4 > ws_size) KS >>= 1;
    const int kslen = DD / KS;

    moirai_gemm<<<NMB * KS, 256, 0, stream>>>(x, W, part, count, kslen);
    moirai_topk<<<NTOK / 4, 256, 0, stream>>>(part, b, out, count, list, KS);
    moirai_fix<<<256, 1024, 0, stream>>>(x, W, b, count, list, out);
}